// Round 1
// baseline (102.439 us; speedup 1.0000x reference)
//
#include <hip/hip_runtime.h>

// KAN Convolutional Layer, bf16 MFMA, MI355X. Round 9.
// x (16,32,64,64) f32 -> out (16, 256, 62, 62) f32.
//
// R8: row-paired 16x16x32 MFMA (D rows 0..7 = convs@row r, 8..15 = convs@row
// r+1), K = 12 taps x 16 slots, 6 MFMA per 2 output rows.
// R9: fuse weight folding into the conv kernel. The folded A-fragment table
// is only 3 KB derived from 2.6 KB of constants; recomputing it per-wave
// (2x float4 + 2 scalar L2-hit loads, ~30 VALU per chunk) is hidden under
// the feature-stage global loads. This removes the serial fold_weights
// <<<1,64>>> launch from the critical path AND all workspace use (the
// harness's 256 MiB ws poison fill was the top dispatch at ~45 us).
//
// Fragment layouts (validated R7/R8): A[m=lane&15][k=(lane>>4)*8+j],
// B[k=(lane>>4)*8+j][n=lane&15], C/D col=lane&15, row=(lane>>4)*4+reg.

typedef __attribute__((ext_vector_type(8))) short bf16x8;
typedef __attribute__((ext_vector_type(4))) float f32x4;

constexpr int Hh = 64, Ww = 64;
constexpr int Ho = 62, Wo = 62;
constexpr int L  = Ho * Wo;          // 3844
constexpr int NC = 8;
constexpr int RPB = 12;              // output rows per block (6 pairs)
constexpr int SR  = RPB + 2;         // staged input rows (max 14)
constexpr int NSTRIP = 6;            // 6*12 = 72 >= 62
constexpr int NPX = SR * Ww;         // 896
constexpr int LDS_PX = NPX + 4;      // +4 px guard for col-overflow reads

__device__ __forceinline__ uint pk(float lo, float hi) {
    return ((__float_as_uint(lo) + 0x8000u) >> 16) |
           ((__float_as_uint(hi) + 0x8000u) & 0xffff0000u);
}

__global__ __launch_bounds__(256, 4)
void kan_conv_kernel(const float* __restrict__ x,
                     const float* __restrict__ bw,
                     const float* __restrict__ sw,
                     const float* __restrict__ scl,
                     float* __restrict__ out)
{
    // per-pixel 32B record (16 bf16: silu, b0..b7, 0...) as 2x uint4;
    // halves XOR-swizzled by (p>>2)&1.
    __shared__ uint4 pix[LDS_PX * 2];            // 28800 B -> 5 blocks/CU

    const int strip = blockIdx.x % NSTRIP;
    const int bc    = blockIdx.x / NSTRIP;       // b*32 + c
    const int s0    = strip * RPB;

    const int wv = threadIdx.x >> 6;     // wave -> column tile
    const int l  = threadIdx.x & 63;
    const int g  = l >> 4;
    const int m  = l & 15;
    const int h  = g & 1;
    const int conv = m & 7;

    // ---- fold weights into A fragments (per-lane, bit-identical to the old
    // fold_weights kernel; overlaps with the feature-stage global loads) ----
    // wa[c][j] = A[m][k = c*32 + g*8 + j]; K: k = tap*16 + slot, tap = kh*3+kw
    // over a 4x3 grid. m<8: conv m, kernel row kh (valid kh<=2); m>=8: conv
    // m-8, kernel row kh-1 (valid kh>=1) -> output row r+1.
    bf16x8 wa[6];
#pragma unroll
    for (int c = 0; c < 6; c++) {
        const int tap = 2 * c + (g >> 1);        // 0..11
        const int kh  = tap / 3, kw = tap % 3;
        const int kh2 = (m < 8) ? kh : kh - 1;
        const bool valid = (kh2 >= 0) && (kh2 <= 2);
        const int idx = valid ? (conv * 9 + kh2 * 3 + kw) : 0;
        const float bwv  = bw[idx];
        const float sclv = valid ? scl[idx] : 0.0f;
        const float4 sa = *(const float4*)(sw + idx * 8);
        const float4 sb = *(const float4*)(sw + idx * 8 + 4);
        float v0, v1, v2, v3, v4, v5, v6, v7;
        if (h == 0) {                            // slots 0..7
            v0 = valid ? bwv : 0.0f;
            v1 = sa.x * sclv; v2 = sa.y * sclv; v3 = sa.z * sclv;
            v4 = sa.w * sclv; v5 = sb.x * sclv; v6 = sb.y * sclv;
            v7 = sb.z * sclv;
        } else {                                 // slots 8..15 (only 8 live)
            v0 = sb.w * sclv;
            v1 = v2 = v3 = v4 = v5 = v6 = v7 = 0.0f;
        }
        uint4 q = make_uint4(pk(v0, v1), pk(v2, v3), pk(v4, v5), pk(v6, v7));
        wa[c] = *(const bf16x8*)&q;
    }

    // ---- feature stage ----
    const int stage_rows = (s0 + SR <= Hh) ? SR : (Hh - s0);
    const int npx = stage_rows * Ww;
    const float* xp = x + (size_t)bc * (Hh * Ww) + (size_t)s0 * Ww;

    for (int p = threadIdx.x; p < npx; p += 256) {
        const float v  = xp[p];
        const float sv = v / (1.0f + __expf(-v));        // silu

        // uniform cubic B-spline closed form; knots (i-3)*0.4-1 -> u=(v+2.2)*2.5
        const float u  = (v + 2.2f) * 2.5f;
        const float fj = floorf(u);
        const float t  = u - fj;
        const int   j  = (int)fj - 3;            // basis slot of tap w0
        const float om = 1.0f - t;
        const float t2 = t * t;
        const float w3 = t * t2 * (1.0f / 6.0f);
        const float w0 = om * om * om * (1.0f / 6.0f);
        const float w1 = fmaf(t2, fmaf(t, 0.5f, -1.0f), 2.0f / 3.0f);
        const float w2 = 1.0f - w0 - w1 - w3;

        float b[8];
#pragma unroll
        for (int s = 0; s < 8; s++) {
            float r = 0.0f;
            r = (j == s    ) ? w0 : r;
            r = (j == s - 1) ? w1 : r;
            r = (j == s - 2) ? w2 : r;
            r = (j == s - 3) ? w3 : r;
            b[s] = r;
        }

        const int sw_ = (p >> 2) & 1;
        pix[p * 2 + sw_]       = make_uint4(pk(sv, b[0]), pk(b[1], b[2]),
                                            pk(b[3], b[4]), pk(b[5], b[6]));
        pix[p * 2 + (1 - sw_)] = make_uint4(pk(b[7], 0.0f), 0u, 0u, 0u);
    }
    __syncthreads();

    // ---- MFMA conv stage ----
    const int pcol = wv * 16 + m;        // B location column

    // per-lane tap pixel offsets per chunk
    int dtap[6];
#pragma unroll
    for (int c = 0; c < 6; c++) {
        const int tap = 2 * c + (g >> 1);        // 0..11
        dtap[c] = (tap / 3) * Ww + (tap % 3);
    }

    const int nrt = (s0 + RPB <= Ho) ? RPB : (Ho - s0);   // 12 or 2 (even)
    const char* pixb = (const char*)pix;
    const int rowoff = g >> 1;           // D rows 8..15 -> output row +1
    const int cbase  = (g & 1) * 4;      // D row within pair -> conv base

    for (int rl = 0; rl < nrt; rl += 2) {
        const int ptile = rl * Ww + pcol;
        f32x4 acc = {0.0f, 0.0f, 0.0f, 0.0f};
#pragma unroll
        for (int c = 0; c < 6; c++) {
            const int p = ptile + dtap[c];
            const int addr = (p << 5) + ((((p >> 2) & 1) ^ h) << 4);
            const bf16x8 bfrag = *(const bf16x8*)(pixb + addr);
            acc = __builtin_amdgcn_mfma_f32_16x16x32_bf16(wa[c], bfrag, acc, 0, 0, 0);
        }

        if (pcol < Wo) {
            float* op = out + ((size_t)bc * NC + cbase) * L
                            + (size_t)(s0 + rl + rowoff) * Wo + pcol;
            op[0 * L] = acc.x;
            op[1 * L] = acc.y;
            op[2 * L] = acc.z;
            op[3 * L] = acc.w;
        }
    }
}

extern "C" void kernel_launch(void* const* d_in, const int* in_sizes, int n_in,
                              void* d_out, int out_size, void* d_ws, size_t ws_size,
                              hipStream_t stream) {
    const float* x   = (const float*)d_in[0];
    const float* bw  = (const float*)d_in[1];
    const float* sw  = (const float*)d_in[2];
    const float* scl = (const float*)d_in[3];
    float* out = (float*)d_out;
    (void)d_ws; (void)ws_size;

    const int planes = in_sizes[0] / (Hh * Ww);  // 512
    dim3 grid(planes * NSTRIP);                  // 3072 blocks
    kan_conv_kernel<<<grid, 256, 0, stream>>>(x, bw, sw, scl, out);
}